// Round 4
// baseline (3644.427 us; speedup 1.0000x reference)
//
#include <hip/hip_runtime.h>
#include <math.h>

// ODE-RNN forward: B=512, K=1024, U=16, P=32, H=128, L=32, TD=64
// v5: intra-wave reductions, 2 lgkm-only barriers/step, no narrow phases.
//
// History: v1 3455us (6 barriers, LDS-reduction phases, VALUBusy 38%).
// v2 chunking 5751us (more phases = worse). v3 2 blocks/CU 18063us (weights
// 245KB/block MUST be register-resident; 2 blocks/CU impossible). v4 (fewer
// barriers, lgkm-only, prefetch) 3610us = NEUTRAL -> stalls are NOT barrier
// drains or staging loads; they are the LDS-round-trip reductions + phases
// where only 1-2 of 8 waves work.
//
// v5 remap:
//  - gates: thread->(j=t>>2, q=t&3); the 4 partials for hidden unit j are in
//    4 ADJACENT LANES of one wave -> 2 __shfl_xor (DPP) reduce; GRU computed
//    redundantly by all 4 lanes; lane q==0 writes h. Per-lane cols = 8 x-cols
//    (8q..8q+8) + 32 h-cols (32q..32q+32) so control flow is uniform.
//  - head: thread->(o=t>>3, e=t&7); 3 __shfl_xor reduce; theta computed in
//    lane groups; group-lane-0 writes thetaL + out_th.
//  - lift/feat-staging/RK4: computed REDUNDANTLY per wave into wave-private
//    LDS (featW[w], xW[w], dtW[w]); y-state replicated per wave. No sync.
//    wave 0 alone stores out_ys. Redundant global u/dt/y_seq loads hit L1.
//  - h double-buffered (hbuf[2]) so gates(k+1)|h(k) vs GRU write h(k+1)
//    never race.
// Per step: P1 stage+lift (wave-local) | P2 gates+GRU -> write h | BAR D |
//           P3 head -> theta | BAR E | P4 RK4+store. 2 barriers total.

// NOTE: macro param must NOT be named `w` — (v).w would be captured.
#define DOT4(acc, v, arr, base)                                           \
  acc += (v).x * (arr)[(base)] + (v).y * (arr)[(base) + 1] +              \
         (v).z * (arr)[(base) + 2] + (v).w * (arr)[(base) + 3];

__device__ __forceinline__ float sigf(float x) {
  return 1.0f / (1.0f + __expf(-x));
}

__device__ __forceinline__ float tanh_fast(float x) {
  float ax = fabsf(x);
  float e = __expf(2.0f * ax);
  float r = 1.0f - 2.0f / (e + 1.0f);
  return copysignf(r, x);
}

// LDS-only producer->consumer barrier: drains lgkmcnt (LDS) but NOT vmcnt,
// so global stores and prefetch loads survive the barrier. (proven v2/v4)
#define BAR()                                            \
  do {                                                   \
    asm volatile("s_waitcnt lgkmcnt(0)" ::: "memory");   \
    __builtin_amdgcn_s_barrier();                        \
    asm volatile("" ::: "memory");                       \
  } while (0)

extern "C" __global__ __launch_bounds__(512, 2) void odernn_kernel(
    const float* __restrict__ y0, const float* __restrict__ u_seq,
    const float* __restrict__ dt_seq, const float* __restrict__ y_seq,
    const float* __restrict__ u2y, const float* __restrict__ lift_W,
    const float* __restrict__ lift_b, const float* __restrict__ w_ih,
    const float* __restrict__ w_hh, const float* __restrict__ b_ih,
    const float* __restrict__ b_hh, const float* __restrict__ head_W,
    const float* __restrict__ head_b, const int* __restrict__ tf_p,
    float* __restrict__ out_ys, float* __restrict__ out_th) {
  __shared__ __align__(16) float hbuf[2][2][128];  // h double-buffer (shared)
  __shared__ __align__(16) float xW[8][2][32];     // x, wave-private
  __shared__ __align__(16) float featW[8][2][48];  // [u(16)|y_in(32)], wave-priv
  __shared__ float dtW[8][2];                      // dt, wave-private
  __shared__ float thetaL[2][64];                  // theta (shared at BAR E)
  __shared__ float liftL[32 * 49];                 // stride 49: conflict-free
  __shared__ float u2yL[16 * 32];

  const int t = threadIdx.x;
  const int wv = t >> 6;     // wave id 0..7
  const int l = t & 63;      // lane in wave
  const int b0 = blockIdx.x * 2;
  const int j = t >> 2;      // hidden unit 0..127 (4 lanes per j, same wave)
  const int q = t & 3;       // col slice: x[8q..8q+8) + h[32q..32q+32)
  const int tfe = *tf_p;

  // ---- register-resident gate weights for (j, q):
  // wr/wz/wn[0..8)  <- w_ih rows {j, j+128, j+256} cols 8q..8q+8
  // wr/wz/wn[8..40) <- w_hh rows {j, j+128, j+256} cols 32q..32q+32
  float wr[40], wz[40], wn[40];
  {
    const int jr = j, jz = j + 128, jn = j + 256;
#pragma unroll
    for (int cc = 0; cc < 8; ++cc) {
      const int c = 8 * q + cc;
      wr[cc] = w_ih[jr * 32 + c];
      wz[cc] = w_ih[jz * 32 + c];
      wn[cc] = w_ih[jn * 32 + c];
    }
#pragma unroll
    for (int cc = 0; cc < 32; ++cc) {
      const int c = 32 * q + cc;
      wr[8 + cc] = w_hh[jr * 128 + c];
      wz[8 + cc] = w_hh[jz * 128 + c];
      wn[8 + cc] = w_hh[jn * 128 + c];
    }
  }
  // head: lane group (o = t>>3) x slice (e = t&7): h[16e..16e+16)
  const int ho = t >> 3;     // 0..63
  const int he = t & 7;
  float wh[16];
#pragma unroll
  for (int i = 0; i < 16; ++i) wh[i] = head_W[ho * 128 + he * 16 + i];

  // biases (per-lane for redundant GRU/head/lift)
  const float bR = b_ih[j] + b_hh[j];
  const float bZ = b_ih[j + 128] + b_hh[j + 128];
  const float bIn = b_ih[j + 256];
  const float bHn = b_hh[j + 256];
  const float hb = head_b[ho];
  const float lb = lift_b[l & 31];

  for (int idx = t; idx < 32 * 48; idx += 512)
    liftL[(idx / 48) * 49 + (idx % 48)] = lift_W[idx];
  u2yL[t] = u2y[t];                  // 512 elements
  (&hbuf[0][0][0])[t] = 0.0f;        // zero both h buffers (512 floats)

  // replicated state: every lane holds y for (bb,jj)=(l>>5,l&31); every lane
  // holds h for its j (4-way redundant within the j-group).
  float yreg = y0[(b0 + (l >> 5)) * 32 + (l & 31)];
  float hreg[2] = {0.0f, 0.0f};

  // prefetch k=0 staging (per wave, redundant; L1-cached)
  float upf = 0.0f, dtpf = 0.0f, ypf = 0.0f;
  if (l < 32) upf = u_seq[((size_t)(b0 + (l >> 4)) * 1024 + 0) * 16 + (l & 15)];
  if (l < 2) dtpf = dt_seq[(size_t)(b0 + l) * 1024 + 0];
  int mtfk = 0;  // k % tfe, maintained incrementally

  __syncthreads();  // liftL/u2yL/hbuf-zero visible

  for (int k = 0; k < 1024; ++k) {
    const int rp = k & 1;  // gates read hbuf[rp] = h(k-1); GRU writes hbuf[rp^1]

    // ---- P1 (wave-local, no sync): stage featW/dtW, prefetch k+1, lift
    {
      const int bb = l >> 5, jj = l & 31;
      if (l < 32) featW[wv][l >> 4][l & 15] = upf;
      if (l < 2) dtW[wv][l] = dtpf;
      float yin = yreg;
      if (k > 0 && mtfk == 0) yin = ypf;  // teacher forcing (prefetched)
      featW[wv][bb][16 + jj] = yin;
      // issue prefetch for k+1 (covered by P2..P4 latency)
      const int kn = (k + 1 < 1024) ? k + 1 : 1023;
      if (l < 32)
        upf = u_seq[((size_t)(b0 + (l >> 4)) * 1024 + kn) * 16 + (l & 15)];
      if (l < 2) dtpf = dt_seq[(size_t)(b0 + l) * 1024 + kn];
      if (mtfk == tfe - 1)  // (k+1)%tfe==0 -> y_tf(k+1)=y_seq[k]
        ypf = y_seq[((size_t)(b0 + bb) * 1024 + k) * 32 + jj];
      // lift: lane computes x[bb][o], o = jj (redundant per wave)
      float a0 = lb, a1 = 0.f, a2 = 0.f, a3 = 0.f;
#pragma unroll
      for (int i = 0; i < 48; i += 4) {
        a0 += featW[wv][bb][i] * liftL[jj * 49 + i];
        a1 += featW[wv][bb][i + 1] * liftL[jj * 49 + i + 1];
        a2 += featW[wv][bb][i + 2] * liftL[jj * 49 + i + 2];
        a3 += featW[wv][bb][i + 3] * liftL[jj * 49 + i + 3];
      }
      float acc = (a0 + a1) + (a2 + a3);
      xW[wv][bb][jj] = acc * sigf(acc);
    }

    // ---- P2: gates (uniform: 2 f4 from xW + 8 f4 from hbuf[rp]) + reduce
    float aR[2], aZ[2], aI[2], aN[2];
#pragma unroll
    for (int bb = 0; bb < 2; ++bb) {
      const float4* xv = reinterpret_cast<const float4*>(&xW[wv][bb][8 * q]);
      const float4* hv =
          reinterpret_cast<const float4*>(&hbuf[rp][bb][32 * q]);
      float r_ = 0.f, z_ = 0.f, i_ = 0.f, n_ = 0.f;
#pragma unroll
      for (int i = 0; i < 2; ++i) {
        float4 v = xv[i];
        DOT4(r_, v, wr, 4 * i)
        DOT4(z_, v, wz, 4 * i)
        DOT4(i_, v, wn, 4 * i)     // x-part of n-gate (i_n)
      }
#pragma unroll
      for (int i = 0; i < 8; ++i) {
        float4 v = hv[i];
        DOT4(r_, v, wr, 8 + 4 * i)
        DOT4(z_, v, wz, 8 + 4 * i)
        DOT4(n_, v, wn, 8 + 4 * i)  // h-part of n-gate (h_n)
      }
      aR[bb] = r_; aZ[bb] = z_; aI[bb] = i_; aN[bb] = n_;
    }
    // reduce across q (4 adjacent lanes): masks 1,2 (quad-perm DPP)
#pragma unroll
    for (int m = 1; m <= 2; m <<= 1) {
#pragma unroll
      for (int bb = 0; bb < 2; ++bb) {
        aR[bb] += __shfl_xor(aR[bb], m, 64);
        aZ[bb] += __shfl_xor(aZ[bb], m, 64);
        aI[bb] += __shfl_xor(aI[bb], m, 64);
        aN[bb] += __shfl_xor(aN[bb], m, 64);
      }
    }
    // GRU elementwise (all 4 lanes redundant; q==0 writes h)
#pragma unroll
    for (int bb = 0; bb < 2; ++bb) {
      float r = sigf(aR[bb] + bR);
      float z = sigf(aZ[bb] + bZ);
      float n = tanh_fast(aI[bb] + bIn + r * (aN[bb] + bHn));
      float hn = (1.0f - z) * n + z * hreg[bb];
      hreg[bb] = hn;
      if (q == 0) hbuf[rp ^ 1][bb][j] = hn;
    }
    BAR();  // D: h(k) visible to all waves

    // ---- P3: head (8-lane groups) -> theta
    float s0, s1;
    {
      const float4* h40 =
          reinterpret_cast<const float4*>(&hbuf[rp ^ 1][0][16 * he]);
      const float4* h41 =
          reinterpret_cast<const float4*>(&hbuf[rp ^ 1][1][16 * he]);
      float a0 = 0.f, a1 = 0.f;
#pragma unroll
      for (int i = 0; i < 4; ++i) {
        float4 v0 = h40[i];
        float4 v1 = h41[i];
        DOT4(a0, v0, wh, 4 * i)
        DOT4(a1, v1, wh, 4 * i)
      }
      s0 = a0; s1 = a1;
    }
#pragma unroll
    for (int m = 1; m <= 4; m <<= 1) {
      s0 += __shfl_xor(s0, m, 64);
      s1 += __shfl_xor(s1, m, 64);
    }
    {
      float th0 = 0.001f + 1.999f * sigf(s0 + hb);
      float th1 = 0.001f + 1.999f * sigf(s1 + hb);
      if (he == 0) {
        thetaL[0][ho] = th0;
        thetaL[1][ho] = th1;
        out_th[(size_t)((b0 + 0) * 1024 + k) * 64 + ho] = th0;
        out_th[(size_t)((b0 + 1) * 1024 + k) * 64 + ho] = th1;
      }
    }
    BAR();  // E: thetaL visible to all waves

    // ---- P4 (wave-local, redundant per wave): jump + RK4; wave0 stores
    {
      const int bb = l >> 5, jj = l & 31;
      float y = yreg;
#pragma unroll
      for (int i = 0; i < 16; ++i) y += featW[wv][bb][i] * u2yL[i * 32 + jj];
      float a = thetaL[bb][jj];
      float b2 = thetaL[bb][32 + jj];
      float hdt = dtW[wv][bb];
      float k1 = b2 - a * y;
      float k2 = b2 - a * (y + 0.5f * hdt * k1);
      float k3 = b2 - a * (y + 0.5f * hdt * k2);
      float k4 = b2 - a * (y + hdt * k3);
      y += hdt * (1.0f / 6.0f) * (k1 + 2.0f * k2 + 2.0f * k3 + k4);
      yreg = y;
      if (wv == 0) out_ys[(size_t)((b0 + bb) * 1024 + k) * 32 + jj] = y;
    }
    mtfk = (mtfk + 1 == tfe) ? 0 : mtfk + 1;
    // no barrier: next P1/P2 touch only wave-private regions and hbuf[rp^1]
    // (ordered by D/E), thetaL rewritten only after next D.
  }
}

extern "C" void kernel_launch(void* const* d_in, const int* in_sizes, int n_in,
                              void* d_out, int out_size, void* d_ws,
                              size_t ws_size, hipStream_t stream) {
  (void)in_sizes; (void)n_in; (void)out_size; (void)d_ws; (void)ws_size;
  const float* y0     = (const float*)d_in[0];
  const float* u_seq  = (const float*)d_in[1];
  const float* dt_seq = (const float*)d_in[2];
  const float* y_seq  = (const float*)d_in[3];
  const float* u2y    = (const float*)d_in[4];
  const float* lift_W = (const float*)d_in[5];
  const float* lift_b = (const float*)d_in[6];
  const float* w_ih   = (const float*)d_in[7];
  const float* w_hh   = (const float*)d_in[8];
  const float* b_ih   = (const float*)d_in[9];
  const float* b_hh   = (const float*)d_in[10];
  const float* head_W = (const float*)d_in[11];
  const float* head_b = (const float*)d_in[12];
  const int*   tf_p   = (const int*)d_in[13];

  float* out_ys = (float*)d_out;
  float* out_th = out_ys + (size_t)512 * 1024 * 32;

  odernn_kernel<<<dim3(256), dim3(512), 0, stream>>>(
      y0, u_seq, dt_seq, y_seq, u2y, lift_W, lift_b, w_ih, w_hh, b_ih, b_hh,
      head_W, head_b, tf_p, out_ys, out_th);
}